// Round 3
// baseline (133.635 us; speedup 1.0000x reference)
//
#include <hip/hip_runtime.h>
#include <hip/hip_bf16.h>
#include <stdint.h>

#define HIDDEN 768
#define NH 12
#define HD 64
#define BB 8
#define SS 128
#define LL 16
#define LS 8
#define TT 136            // SS + LS
#define NROWS 1152        // BB*SS + LL*LS rows of the unique-row Xcat
#define BH (BB * NH)      // 96

typedef __attribute__((ext_vector_type(8))) short bf16x8;
typedef __attribute__((ext_vector_type(4))) float f32x4;
typedef __attribute__((ext_vector_type(16))) float f32x16;
typedef __hip_bfloat16 bf16;

__device__ inline float tof(bf16 x) { return __bfloat162float(x); }
__device__ inline uint16_t b16bits(float f) {
    bf16 h = __float2bfloat16(f);
    union { bf16 h; uint16_t u; } u; u.h = h; return u.u;
}

// ---------------------------------------------------------------------------
// One-shot f32 -> bf16 cast of X ([tok;lab] -> Xb[1152][768]) and W
// ([Wq;Wk;Wv] -> Wb[2304][768]).
// ---------------------------------------------------------------------------
#define TOK_V4 196608     // 8*128*768/4
#define XB_V4  221184     // + 16*8*768/4
#define W_V4   147456     // 768*768/4
__global__ __launch_bounds__(256) void cast_kernel(
    const float* __restrict__ tok, const float* __restrict__ lab,
    const float* __restrict__ Wq, const float* __restrict__ Wk,
    const float* __restrict__ Wv,
    uint16_t* __restrict__ Xb, uint16_t* __restrict__ Wb)
{
    int g = blockIdx.x * 256 + threadIdx.x;
    float4 v;
    ushort4* d;
    if (g < XB_V4) {
        v = (g < TOK_V4) ? reinterpret_cast<const float4*>(tok)[g]
                         : reinterpret_cast<const float4*>(lab)[g - TOK_V4];
        d = reinterpret_cast<ushort4*>(Xb) + g;
    } else {
        int w = g - XB_V4;
        v = (w < W_V4)     ? reinterpret_cast<const float4*>(Wq)[w]
          : (w < 2 * W_V4) ? reinterpret_cast<const float4*>(Wk)[w - W_V4]
                           : reinterpret_cast<const float4*>(Wv)[w - 2 * W_V4];
        d = reinterpret_cast<ushort4*>(Wb) + w;
    }
    ushort4 h;
    h.x = b16bits(v.x); h.y = b16bits(v.y); h.z = b16bits(v.z); h.w = b16bits(v.w);
    *d = h;
}

// ---------------------------------------------------------------------------
// QKV projection: C[1152,2304] = Xb @ Wb^T + bias, bf16 inputs. 64x128 tile,
// BK=64, double-buffered LDS + register prefetch.
// ---------------------------------------------------------------------------
__global__ __launch_bounds__(256) void qkv_kernel(
    const uint16_t* __restrict__ Xb, const uint16_t* __restrict__ Wb,
    const float* __restrict__ bq, const float* __restrict__ bk,
    const float* __restrict__ bv,
    bf16* __restrict__ Qw, bf16* __restrict__ Kw, bf16* __restrict__ Vw)
{
    __shared__ __align__(16) uint16_t As[2][64 * 72];    // 2 x  9216 B
    __shared__ __align__(16) uint16_t Bs[2][128 * 72];   // 2 x 18432 B

    int tid = threadIdx.x;
    int lane = tid & 63, wv = tid >> 6;
    int ml = lane & 15, quad = lane >> 4;
    int mt = blockIdx.x / 18, nt = blockIdx.x % 18;
    int wr = wv >> 1, wc = wv & 1;

    int mat = nt / 6;
    int col0 = (nt % 6) * 128;
    const float* bptr = (mat == 0) ? bq : ((mat == 1) ? bk : bv);
    bf16* obase       = (mat == 0) ? Qw : ((mat == 1) ? Kw : Vw);

    const uint16_t* asrc = Xb + (size_t)mt * 64 * HIDDEN;
    const uint16_t* bsrc = Wb + (size_t)nt * 128 * HIDDEN;

    int ar_[2], ac_[2], br_[4], bc_[4];
    #pragma unroll
    for (int i = 0; i < 2; ++i) { int g = i * 256 + tid; ar_[i] = g >> 3; ac_[i] = (g & 7) * 8; }
    #pragma unroll
    for (int i = 0; i < 4; ++i) { int g = i * 256 + tid; br_[i] = g >> 3; bc_[i] = (g & 7) * 8; }

    bf16x8 ra[2], rb[4];
    #pragma unroll
    for (int i = 0; i < 2; ++i)
        ra[i] = *reinterpret_cast<const bf16x8*>(asrc + (size_t)ar_[i] * HIDDEN + ac_[i]);
    #pragma unroll
    for (int i = 0; i < 4; ++i)
        rb[i] = *reinterpret_cast<const bf16x8*>(bsrc + (size_t)br_[i] * HIDDEN + bc_[i]);

    f32x4 acc[2][4] = {};
    int p = 0;

    for (int k0 = 0; k0 < HIDDEN; k0 += 64) {
        #pragma unroll
        for (int i = 0; i < 2; ++i)
            *reinterpret_cast<bf16x8*>(&As[p][ar_[i] * 72 + ac_[i]]) = ra[i];
        #pragma unroll
        for (int i = 0; i < 4; ++i)
            *reinterpret_cast<bf16x8*>(&Bs[p][br_[i] * 72 + bc_[i]]) = rb[i];
        __syncthreads();

        if (k0 + 64 < HIDDEN) {
            #pragma unroll
            for (int i = 0; i < 2; ++i)
                ra[i] = *reinterpret_cast<const bf16x8*>(asrc + (size_t)ar_[i] * HIDDEN + k0 + 64 + ac_[i]);
            #pragma unroll
            for (int i = 0; i < 4; ++i)
                rb[i] = *reinterpret_cast<const bf16x8*>(bsrc + (size_t)br_[i] * HIDDEN + k0 + 64 + bc_[i]);
        }

        #pragma unroll
        for (int kh = 0; kh < 2; ++kh) {
            bf16x8 af[2], bfr[4];
            #pragma unroll
            for (int rt = 0; rt < 2; ++rt)
                af[rt] = *reinterpret_cast<const bf16x8*>(&As[p][(wr * 32 + rt * 16 + ml) * 72 + kh * 32 + quad * 8]);
            #pragma unroll
            for (int ct = 0; ct < 4; ++ct)
                bfr[ct] = *reinterpret_cast<const bf16x8*>(&Bs[p][(wc * 64 + ct * 16 + ml) * 72 + kh * 32 + quad * 8]);
            #pragma unroll
            for (int rt = 0; rt < 2; ++rt)
                #pragma unroll
                for (int ct = 0; ct < 4; ++ct)
                    acc[rt][ct] = __builtin_amdgcn_mfma_f32_16x16x32_bf16(af[rt], bfr[ct], acc[rt][ct], 0, 0, 0);
        }
        p ^= 1;
    }

    #pragma unroll
    for (int ct = 0; ct < 4; ++ct) {
        int c = col0 + wc * 64 + ct * 16 + ml;
        float bvv = bptr[c];
        #pragma unroll
        for (int rt = 0; rt < 2; ++rt) {
            #pragma unroll
            for (int reg = 0; reg < 4; ++reg) {
                int R = mt * 64 + wr * 32 + rt * 16 + quad * 4 + reg;
                obase[(size_t)R * HIDDEN + c] = __float2bfloat16(acc[rt][ct][reg] + bvv);
            }
        }
    }
}

// ---------------------------------------------------------------------------
// Phase A: token-token attention once per (b,h). V^T staged via coalesced
// u32 row reads + packed LDS transpose writes; hf==0 block spills V^T to ws.
// ---------------------------------------------------------------------------
__global__ __launch_bounds__(256) void attn_tt_kernel(
    const bf16* __restrict__ Qw, const bf16* __restrict__ Kw,
    const bf16* __restrict__ Vw, const float* __restrict__ tmask,
    bf16* __restrict__ ctx_tt, float* __restrict__ m_tt, float* __restrict__ d_tt,
    uint32_t* __restrict__ Vt_g)
{
    __shared__ __align__(16) uint32_t KldsW[128 * 36];
    __shared__ __align__(16) uint32_t VtW[64 * 68];
    __shared__ __align__(16) uint32_t PW[4][16 * 68];
    __shared__ float bias_s[128];

    int bh = blockIdx.x >> 1;
    int hf = blockIdx.x & 1;
    int b = bh / NH, h = bh % NH;
    int tid = threadIdx.x;
    int lane = tid & 63, wv = tid >> 6;
    int ml = lane & 15, quad = lane >> 4;

    for (int i = tid; i < 128 * 32; i += 256) {
        int s = i >> 5, w = i & 31;
        KldsW[s * 36 + w] =
            reinterpret_cast<const uint32_t*>(Kw + (size_t)(b * SS + s) * HIDDEN + h * HD)[w];
    }
    #pragma unroll
    for (int c = 0; c < 8; ++c) {
        int g = c * 256 + tid;             // 0..2047
        int s2 = g >> 5, dw = g & 31;
        const uint32_t* v0 = reinterpret_cast<const uint32_t*>(Vw + (size_t)(b * SS + 2 * s2) * HIDDEN + h * HD);
        const uint32_t* v1 = reinterpret_cast<const uint32_t*>(Vw + (size_t)(b * SS + 2 * s2 + 1) * HIDDEN + h * HD);
        uint32_t a = v0[dw], bb = v1[dw];
        VtW[(2 * dw) * 68 + s2]     = (a & 0xffffu) | ((bb & 0xffffu) << 16);
        VtW[(2 * dw + 1) * 68 + s2] = (a >> 16) | (bb & 0xffff0000u);
    }
    for (int i = tid; i < 128; i += 256)
        bias_s[i] = (1.0f - tmask[b * SS + i]) * -10000.0f;
    __syncthreads();

    if (hf == 0) {
        uint32_t* vg = Vt_g + (size_t)bh * 4096;
        #pragma unroll
        for (int c = 0; c < 16; ++c) {
            int g = c * 256 + tid;
            vg[g] = VtW[(g >> 6) * 68 + (g & 63)];
        }
    }

    const bf16* Klb = reinterpret_cast<const bf16*>(KldsW);
    const bf16* Vtb = reinterpret_cast<const bf16*>(VtW);
    const bf16* Pb  = reinterpret_cast<const bf16*>(PW[wv]);

    int qr = hf * 64 + wv * 16 + ml;
    const bf16* qp = Qw + (size_t)(b * SS + qr) * HIDDEN + h * HD + quad * 8;
    bf16x8 a0 = *reinterpret_cast<const bf16x8*>(qp);
    bf16x8 a1 = *reinterpret_cast<const bf16x8*>(qp + 32);

    f32x4 sc[8];
    #pragma unroll
    for (int ct = 0; ct < 8; ++ct) {
        const bf16* kp = Klb + (ct * 16 + ml) * 72 + quad * 8;
        bf16x8 b0 = *reinterpret_cast<const bf16x8*>(kp);
        bf16x8 b1 = *reinterpret_cast<const bf16x8*>(kp + 32);
        f32x4 z = {0.f, 0.f, 0.f, 0.f};
        z = __builtin_amdgcn_mfma_f32_16x16x32_bf16(a0, b0, z, 0, 0, 0);
        z = __builtin_amdgcn_mfma_f32_16x16x32_bf16(a1, b1, z, 0, 0, 0);
        sc[ct] = z;
    }

    float mx[4] = {-1e30f, -1e30f, -1e30f, -1e30f};
    #pragma unroll
    for (int ct = 0; ct < 8; ++ct) {
        float bc = bias_s[ct * 16 + ml];
        #pragma unroll
        for (int reg = 0; reg < 4; ++reg) {
            float v = sc[ct][reg] * 0.125f + bc;
            sc[ct][reg] = v;
            mx[reg] = fmaxf(mx[reg], v);
        }
    }
    #pragma unroll
    for (int reg = 0; reg < 4; ++reg)
        #pragma unroll
        for (int off = 1; off < 16; off <<= 1)
            mx[reg] = fmaxf(mx[reg], __shfl_xor(mx[reg], off));

    float Zs[4] = {0.f, 0.f, 0.f, 0.f};
    #pragma unroll
    for (int ct = 0; ct < 8; ++ct) {
        #pragma unroll
        for (int reg = 0; reg < 4; ++reg) {
            float e = __expf(sc[ct][reg] - mx[reg]);
            sc[ct][reg] = e;
            Zs[reg] += e;
        }
    }
    #pragma unroll
    for (int reg = 0; reg < 4; ++reg)
        #pragma unroll
        for (int off = 1; off < 16; off <<= 1)
            Zs[reg] += __shfl_xor(Zs[reg], off);

    #pragma unroll
    for (int reg = 0; reg < 4; ++reg) {
        int gr = bh * 128 + hf * 64 + wv * 16 + quad * 4 + reg;
        if (ml == 0) { m_tt[gr] = mx[reg]; d_tt[gr] = Zs[reg]; }
    }

    #pragma unroll
    for (int ct = 0; ct < 8; ++ct) {
        #pragma unroll
        for (int reg = 0; reg < 4; ++reg) {
            float e = sc[ct][reg];
            float ep = __shfl_xor(e, 1);
            if ((ml & 1) == 0)
                PW[wv][(quad * 4 + reg) * 68 + ct * 8 + (ml >> 1)] =
                    (uint32_t)b16bits(e) | ((uint32_t)b16bits(ep) << 16);
        }
    }

    float rZ[4];
    #pragma unroll
    for (int reg = 0; reg < 4; ++reg) rZ[reg] = 1.0f / Zs[reg];

    #pragma unroll
    for (int ct4 = 0; ct4 < 4; ++ct4) {
        f32x4 acc = {0.f, 0.f, 0.f, 0.f};
        #pragma unroll
        for (int ks = 0; ks < 4; ++ks) {
            bf16x8 ap = *reinterpret_cast<const bf16x8*>(Pb + ml * 136 + ks * 32 + quad * 8);
            bf16x8 bp = *reinterpret_cast<const bf16x8*>(Vtb + (ct4 * 16 + ml) * 136 + ks * 32 + quad * 8);
            acc = __builtin_amdgcn_mfma_f32_16x16x32_bf16(ap, bp, acc, 0, 0, 0);
        }
        #pragma unroll
        for (int reg = 0; reg < 4; ++reg) {
            int gr = bh * 128 + hf * 64 + wv * 16 + quad * 4 + reg;
            ctx_tt[(size_t)gr * 64 + ct4 * 16 + ml] = __float2bfloat16(acc[reg] * rZ[reg]);
        }
    }
}

// ---------------------------------------------------------------------------
// Phase B: 384 blocks, each handles TWO label-pairs (lp = pp, pp+4) for one
// (b,h): token V^T / m,d / bias staged once per block; both items' label
// V-cols staged up front (item1 occupies the former zero-pad slot; the
// corresponding P positions are zeroed per item, so PV math is unchanged).
// Token-Q and ctx_tt reads hoisted across the two items (rt-outer loop).
// ---------------------------------------------------------------------------
__global__ __launch_bounds__(256) void attn_merge_kernel(
    const bf16* __restrict__ Qw, const bf16* __restrict__ Kw,
    const bf16* __restrict__ Vw, const uint32_t* __restrict__ Vt_g,
    const bf16* __restrict__ ctx_tt, const float* __restrict__ m_tt,
    const float* __restrict__ d_tt,
    const float* __restrict__ tmask, const float* __restrict__ lmask,
    float* __restrict__ out)
{
    __shared__ __align__(16) uint32_t VtW[64 * 84];     // 21504 B
    __shared__ __align__(16) uint32_t PWL[16 * 84];     //  5376 B (wave-3 label P)
    __shared__ __align__(16) uint32_t P2W[3][32 * 8];   //  3072 B (token P)
    __shared__ float wtab[3][32], itab[3][32];
    __shared__ float mtt_s[128], dtt_s[128], bias_t[128];
    __shared__ float bias_l[2][16];

    int bh = blockIdx.x % 96, pp = blockIdx.x / 96;   // items lp = pp, pp+4
    int b = bh / NH, h = bh % NH;
    int tid = threadIdx.x;
    int lane = tid & 63, wvi = tid >> 6;
    int ml = lane & 15, quad = lane >> 4;
    int hl = lane & 31, hi = lane >> 5;

    // token cols 0..127: coalesced copy from Vt_g (L2-hot)
    {
        const uint32_t* vg = Vt_g + (size_t)bh * 4096;
        #pragma unroll
        for (int c = 0; c < 16; ++c) {
            int g = c * 256 + tid;
            VtW[(g >> 6) * 84 + (g & 63)] = vg[g];
        }
    }
    // label cols for BOTH items: item it at u32 cols 64+it*8 .. 71+it*8
    for (int g = tid; g < 1024; g += 256) {
        int d = g >> 4, slot = g & 15;
        int it = slot >> 3, jj = slot & 7;
        int lp = pp + it * 4;
        int l0 = 2 * lp, l1 = l0 + 1;
        int s0 = 128 + 2 * jj, s1 = s0 + 1;
        int r0 = (s0 < 136) ? (1024 + l0 * LS + (s0 - 128)) : (1024 + l1 * LS + (s0 - 136));
        int r1 = (s1 < 136) ? (1024 + l0 * LS + (s1 - 128)) : (1024 + l1 * LS + (s1 - 136));
        uint16_t lo  = reinterpret_cast<const uint16_t*>(Vw + (size_t)r0 * HIDDEN + h * HD)[d];
        uint16_t hi2 = reinterpret_cast<const uint16_t*>(Vw + (size_t)r1 * HIDDEN + h * HD)[d];
        VtW[d * 84 + 64 + it * 8 + jj] = (uint32_t)lo | ((uint32_t)hi2 << 16);
    }
    if (tid < 128) {
        mtt_s[tid] = m_tt[bh * 128 + tid];
        dtt_s[tid] = d_tt[bh * 128 + tid];
        bias_t[tid] = (1.0f - tmask[b * SS + tid]) * -10000.0f;
    }
    if (tid < 32) {
        int it = tid >> 4, j = tid & 15;
        int lp = pp + it * 4;
        int labk = (j < 8) ? (2 * lp * LS + j) : ((2 * lp + 1) * LS + j - 8);
        bias_l[it][j] = (1.0f - lmask[labk]) * -10000.0f;
    }
    __syncthreads();

    const bf16* Vtb = reinterpret_cast<const bf16*>(VtW);

    // preload label-K fragments for both items (all waves)
    bf16x8 kbA[2], kbB[2];
    #pragma unroll
    for (int it = 0; it < 2; ++it) {
        int lp = pp + it * 4;
        int l0 = 2 * lp, l1 = l0 + 1;
        int kprow = 1024 + ((ml < 8) ? (l0 * LS + ml) : (l1 * LS + ml - 8));
        const bf16* kpp = Kw + (size_t)kprow * HIDDEN + h * HD + quad * 8;
        kbA[it] = *reinterpret_cast<const bf16x8*>(kpp);
        kbB[it] = *reinterpret_cast<const bf16x8*>(kpp + 32);
    }

    if (wvi < 3) {
        const bf16* P2b = reinterpret_cast<const bf16*>(P2W[wvi]);
        for (int rt = wvi; rt < 8; rt += 3) {
            int tq = rt * 16 + ml;
            const bf16* qp = Qw + (size_t)(b * SS + tq) * HIDDEN + h * HD + quad * 8;
            bf16x8 a0 = *reinterpret_cast<const bf16x8*>(qp);
            bf16x8 a1 = *reinterpret_cast<const bf16x8*>(qp + 32);

            // ctx rows for this rt (shared by both items)
            float cv0[8], cv1[8];
            #pragma unroll
            for (int reg = 0; reg < 8; ++reg) {
                int row = (reg & 3) + 8 * (reg >> 2) + 4 * hi;
                const bf16* cp = ctx_tt + (size_t)(bh * 128 + rt * 16 + row) * 64;
                cv0[reg] = tof(cp[hl]);
                cv1[reg] = tof(cp[32 + hl]);
            }

            #pragma unroll
            for (int it = 0; it < 2; ++it) {
                int lp = pp + it * 4;
                int l0 = 2 * lp, l1 = l0 + 1;

                f32x4 z = {0.f, 0.f, 0.f, 0.f};
                z = __builtin_amdgcn_mfma_f32_16x16x32_bf16(a0, kbA[it], z, 0, 0, 0);
                z = __builtin_amdgcn_mfma_f32_16x16x32_bf16(a1, kbB[it], z, 0, 0, 0);

                #pragma unroll
                for (int reg = 0; reg < 4; ++reg) {
                    int trow = quad * 4 + reg;
                    float s = z[reg] * 0.125f + bias_l[it][ml];
                    float m = s;
                    m = fmaxf(m, __shfl_xor(m, 1));
                    m = fmaxf(m, __shfl_xor(m, 2));
                    m = fmaxf(m, __shfl_xor(m, 4));
                    float mtt = mtt_s[rt * 16 + trow], dtt = dtt_s[rt * 16 + trow];
                    float m_new = fmaxf(mtt, m);
                    float e = __expf(s - m_new);
                    float dh = e;
                    dh += __shfl_xor(dh, 1);
                    dh += __shfl_xor(dh, 2);
                    dh += __shfl_xor(dh, 4);
                    float alpha = __expf(mtt - m_new);
                    float w = alpha * dtt;
                    float inv = 1.0f / (w + dh);
                    if (ml == 0) { wtab[wvi][trow] = w;      itab[wvi][trow] = inv; }
                    if (ml == 8) { wtab[wvi][16 + trow] = w; itab[wvi][16 + trow] = inv; }
                    float ep = __shfl_xor(e, 1);
                    if ((ml & 1) == 0) {
                        uint32_t pk = (uint32_t)b16bits(e) | ((uint32_t)b16bits(ep) << 16);
                        P2W[wvi][trow * 8 + (ml >> 1)]        = (ml < 8) ? pk : 0u;
                        P2W[wvi][(16 + trow) * 8 + (ml >> 1)] = (ml < 8) ? 0u : pk;
                    }
                }

                bf16x8 ap  = *reinterpret_cast<const bf16x8*>(P2b + hl * 16 + hi * 8);
                bf16x8 bv0 = *reinterpret_cast<const bf16x8*>(Vtb + hl * 168 + 128 + it * 16 + hi * 8);
                bf16x8 bv1 = *reinterpret_cast<const bf16x8*>(Vtb + (32 + hl) * 168 + 128 + it * 16 + hi * 8);
                f32x16 c0 = {}, c1 = {};
                c0 = __builtin_amdgcn_mfma_f32_32x32x16_bf16(ap, bv0, c0, 0, 0, 0);
                c1 = __builtin_amdgcn_mfma_f32_32x32x16_bf16(ap, bv1, c1, 0, 0, 0);

                #pragma unroll
                for (int reg = 0; reg < 16; ++reg) {
                    int row = (reg & 3) + 8 * (reg >> 2) + 4 * hi;
                    int trow = row & 15;
                    int lsel = (row < 16) ? l0 : l1;
                    float w = wtab[wvi][row], inv = itab[wvi][row];
                    float c0v = (reg < 8) ? cv0[reg] : cv0[reg - 8];
                    float c1v = (reg < 8) ? cv1[reg] : cv1[reg - 8];
                    size_t ob = (((size_t)b * TT + rt * 16 + trow) * LL + lsel) * HIDDEN + h * HD;
                    out[ob + hl]      = (w * c0v + c0[reg]) * inv;
                    out[ob + 32 + hl] = (w * c1v + c1[reg]) * inv;
                }
            }
        }
    } else {
        const bf16* Pb = reinterpret_cast<const bf16*>(PWL);
        #pragma unroll
        for (int it = 0; it < 2; ++it) {
            int lp = pp + it * 4;
            int l0 = 2 * lp, l1 = l0 + 1;

            // zero the complementary item's P slot (positions 128+16*(1-it)..)
            for (int z2 = lane; z2 < 128; z2 += 64) {
                int row = z2 >> 3, col = z2 & 7;
                PWL[row * 84 + 64 + (1 - it) * 8 + col] = 0;
            }

            int qrow = 1024 + ((ml < 8) ? (l0 * LS + ml) : (l1 * LS + ml - 8));
            const bf16* qp = Qw + (size_t)qrow * HIDDEN + h * HD + quad * 8;
            bf16x8 a0 = *reinterpret_cast<const bf16x8*>(qp);
            bf16x8 a1 = *reinterpret_cast<const bf16x8*>(qp + 32);

            f32x4 sc[9];
            #pragma unroll
            for (int ct = 0; ct < 9; ++ct) {
                bf16x8 b0, b1;
                if (ct < 8) {
                    const bf16* kp = Kw + (size_t)(b * SS + ct * 16 + ml) * HIDDEN + h * HD + quad * 8;
                    b0 = *reinterpret_cast<const bf16x8*>(kp);
                    b1 = *reinterpret_cast<const bf16x8*>(kp + 32);
                } else { b0 = kbA[it]; b1 = kbB[it]; }
                f32x4 zz = {0.f, 0.f, 0.f, 0.f};
                zz = __builtin_amdgcn_mfma_f32_16x16x32_bf16(a0, b0, zz, 0, 0, 0);
                zz = __builtin_amdgcn_mfma_f32_16x16x32_bf16(a1, b1, zz, 0, 0, 0);
                sc[ct] = zz;
            }

            float mx[4] = {-1e30f, -1e30f, -1e30f, -1e30f};
            #pragma unroll
            for (int ct = 0; ct < 9; ++ct) {
                #pragma unroll
                for (int reg = 0; reg < 4; ++reg) {
                    int rq = quad * 4 + reg;
                    float bc = (ct < 8) ? bias_t[ct * 16 + ml]
                                        : (((rq < 8) != (ml < 8)) ? -1e30f : bias_l[it][ml]);
                    float v = sc[ct][reg] * 0.125f + bc;
                    sc[ct][reg] = v;
                    mx[reg] = fmaxf(mx[reg], v);
                }
            }
            #pragma unroll
            for (int reg = 0; reg < 4; ++reg)
                #pragma unroll
                for (int off = 1; off < 16; off <<= 1)
                    mx[reg] = fmaxf(mx[reg], __shfl_xor(mx[reg], off));

            float Zs[4] = {0.f, 0.f, 0.f, 0.f};
            #pragma unroll
            for (int ct = 0; ct < 9; ++ct) {
                #pragma unroll
                for (int reg = 0; reg < 4; ++reg) {
                    float e = __expf(sc[ct][reg] - mx[reg]);
                    sc[ct][reg] = e;
                    Zs[reg] += e;
                }
            }
            #pragma unroll
            for (int reg = 0; reg < 4; ++reg)
                #pragma unroll
                for (int off = 1; off < 16; off <<= 1)
                    Zs[reg] += __shfl_xor(Zs[reg], off);
            float zi[4];
            #pragma unroll
            for (int reg = 0; reg < 4; ++reg) zi[reg] = 1.0f / Zs[reg];

            #pragma unroll
            for (int ct = 0; ct < 9; ++ct) {
                int cbase = (ct < 8) ? ct * 8 : (64 + it * 8);
                #pragma unroll
                for (int reg = 0; reg < 4; ++reg) {
                    float e = sc[ct][reg];
                    float ep = __shfl_xor(e, 1);
                    if ((ml & 1) == 0)
                        PWL[(quad * 4 + reg) * 84 + cbase + (ml >> 1)] =
                            (uint32_t)b16bits(e) | ((uint32_t)b16bits(ep) << 16);
                }
            }

            #pragma unroll
            for (int ct4 = 0; ct4 < 4; ++ct4) {
                f32x4 acc = {0.f, 0.f, 0.f, 0.f};
                #pragma unroll
                for (int ks = 0; ks < 5; ++ks) {
                    bf16x8 ap = *reinterpret_cast<const bf16x8*>(Pb + ml * 168 + ks * 32 + quad * 8);
                    bf16x8 bp = *reinterpret_cast<const bf16x8*>(Vtb + (ct4 * 16 + ml) * 168 + ks * 32 + quad * 8);
                    acc = __builtin_amdgcn_mfma_f32_16x16x32_bf16(ap, bp, acc, 0, 0, 0);
                }
                #pragma unroll
                for (int reg = 0; reg < 4; ++reg) {
                    int rq = quad * 4 + reg;
                    int l = (rq < 8) ? l0 : l1;
                    int t = SS + (rq & 7);
                    out[(((size_t)b * TT + t) * LL + l) * HIDDEN + h * HD + ct4 * 16 + ml] =
                        acc[reg] * zi[reg];
                }
            }
        }
    }
}

extern "C" void kernel_launch(void* const* d_in, const int* in_sizes, int n_in,
                              void* d_out, int out_size, void* d_ws, size_t ws_size,
                              hipStream_t stream)
{
    const float* tok   = (const float*)d_in[0];
    const float* lab   = (const float*)d_in[1];
    const float* tmask = (const float*)d_in[2];
    const float* lmask = (const float*)d_in[3];
    const float* Wq    = (const float*)d_in[4];
    const float* bq    = (const float*)d_in[5];
    const float* Wk    = (const float*)d_in[6];
    const float* bk    = (const float*)d_in[7];
    const float* Wv    = (const float*)d_in[8];
    const float* bv    = (const float*)d_in[9];

    // ws: Q/K/V bf16 (5,308,416) + ctx_tt bf16 (1,572,864) + m/d f32 (98,304)
    //     + Vt_g u32 (1,572,864) + Xb bf16 (1,769,472) + Wb bf16 (3,538,944)
    //     = 13,860,864 B.
    bf16* Qw = (bf16*)d_ws;
    bf16* Kw = Qw + (size_t)NROWS * HIDDEN;
    bf16* Vw = Kw + (size_t)NROWS * HIDDEN;
    bf16* ctx = Vw + (size_t)NROWS * HIDDEN;
    float* m_tt = (float*)(ctx + (size_t)BH * 128 * 64);
    float* d_tt = m_tt + BH * 128;
    uint32_t* Vt_g = (uint32_t*)(d_tt + BH * 128);
    uint16_t* Xb = (uint16_t*)(Vt_g + (size_t)BH * 4096);
    uint16_t* Wb = Xb + (size_t)NROWS * HIDDEN;

    cast_kernel<<<dim3(2592), 256, 0, stream>>>(tok, lab, Wq, Wk, Wv, Xb, Wb);
    qkv_kernel<<<dim3(18 * 18), 256, 0, stream>>>(
        Xb, Wb, bq, bk, bv, Qw, Kw, Vw);
    attn_tt_kernel<<<dim3(BH * 2), 256, 0, stream>>>(
        Qw, Kw, Vw, tmask, ctx, m_tt, d_tt, Vt_g);
    attn_merge_kernel<<<dim3(384), 256, 0, stream>>>(
        Qw, Kw, Vw, Vt_g, ctx, m_tt, d_tt, tmask, lmask, (float*)d_out);
}

// Round 4
// 132.955 us; speedup vs baseline: 1.0051x; 1.0051x over previous
//
#include <hip/hip_runtime.h>
#include <hip/hip_bf16.h>
#include <stdint.h>

#define HIDDEN 768
#define NH 12
#define HD 64
#define BB 8
#define SS 128
#define LL 16
#define LS 8
#define TT 136            // SS + LS
#define NROWS 1152        // BB*SS + LL*LS rows of the unique-row Xcat
#define BH (BB * NH)      // 96

typedef __attribute__((ext_vector_type(8))) short bf16x8;
typedef __attribute__((ext_vector_type(4))) float f32x4;
typedef __attribute__((ext_vector_type(16))) float f32x16;
typedef __hip_bfloat16 bf16;

__device__ inline float tof(bf16 x) { return __bfloat162float(x); }
__device__ inline uint16_t b16bits(float f) {
    bf16 h = __float2bfloat16(f);
    union { bf16 h; uint16_t u; } u; u.h = h; return u.u;
}

// ---------------------------------------------------------------------------
// One-shot f32 -> bf16 cast of X ([tok;lab] -> Xb[1152][768]) and W
// ([Wq;Wk;Wv] -> Wb[2304][768]).
// ---------------------------------------------------------------------------
#define TOK_V4 196608     // 8*128*768/4
#define XB_V4  221184     // + 16*8*768/4
#define W_V4   147456     // 768*768/4
__global__ __launch_bounds__(256) void cast_kernel(
    const float* __restrict__ tok, const float* __restrict__ lab,
    const float* __restrict__ Wq, const float* __restrict__ Wk,
    const float* __restrict__ Wv,
    uint16_t* __restrict__ Xb, uint16_t* __restrict__ Wb)
{
    int g = blockIdx.x * 256 + threadIdx.x;
    float4 v;
    ushort4* d;
    if (g < XB_V4) {
        v = (g < TOK_V4) ? reinterpret_cast<const float4*>(tok)[g]
                         : reinterpret_cast<const float4*>(lab)[g - TOK_V4];
        d = reinterpret_cast<ushort4*>(Xb) + g;
    } else {
        int w = g - XB_V4;
        v = (w < W_V4)     ? reinterpret_cast<const float4*>(Wq)[w]
          : (w < 2 * W_V4) ? reinterpret_cast<const float4*>(Wk)[w - W_V4]
                           : reinterpret_cast<const float4*>(Wv)[w - 2 * W_V4];
        d = reinterpret_cast<ushort4*>(Wb) + w;
    }
    ushort4 h;
    h.x = b16bits(v.x); h.y = b16bits(v.y); h.z = b16bits(v.z); h.w = b16bits(v.w);
    *d = h;
}

// ---------------------------------------------------------------------------
// QKV projection: C[1152,2304] = Xb @ Wb^T + bias, bf16 inputs.
// 32x128 tile (648 blocks, 2.5/CU; was 64x128 = 324 blocks at 1.27/CU whose
// imbalance cost ~1.6x makespan and left barrier drains unhidden). BK=64,
// double-buffered LDS + register prefetch, 46 KB LDS -> 3 blocks/CU fit.
// ---------------------------------------------------------------------------
__global__ __launch_bounds__(256) void qkv_kernel(
    const uint16_t* __restrict__ Xb, const uint16_t* __restrict__ Wb,
    const float* __restrict__ bq, const float* __restrict__ bk,
    const float* __restrict__ bv,
    bf16* __restrict__ Qw, bf16* __restrict__ Kw, bf16* __restrict__ Vw)
{
    __shared__ __align__(16) uint16_t As[2][32 * 72];    // 2 x  4608 B
    __shared__ __align__(16) uint16_t Bs[2][128 * 72];   // 2 x 18432 B

    int tid = threadIdx.x;
    int lane = tid & 63, wv = tid >> 6;
    int ml = lane & 15, quad = lane >> 4;
    int mt = blockIdx.x / 18, nt = blockIdx.x % 18;   // mt 0..35
    int wr = wv >> 1, wc = wv & 1;

    int mat = nt / 6;
    int col0 = (nt % 6) * 128;
    const float* bptr = (mat == 0) ? bq : ((mat == 1) ? bk : bv);
    bf16* obase       = (mat == 0) ? Qw : ((mat == 1) ? Kw : Vw);

    const uint16_t* asrc = Xb + (size_t)mt * 32 * HIDDEN;
    const uint16_t* bsrc = Wb + (size_t)nt * 128 * HIDDEN;

    // staging coords: A = 32x64 bf16 (256 x 16B, 1/thread), B = 128x64 (4/thread)
    int ar0 = tid >> 3, ac0 = (tid & 7) * 8;
    int br_[4], bc_[4];
    #pragma unroll
    for (int i = 0; i < 4; ++i) { int g = i * 256 + tid; br_[i] = g >> 3; bc_[i] = (g & 7) * 8; }

    bf16x8 ra, rb[4];
    ra = *reinterpret_cast<const bf16x8*>(asrc + (size_t)ar0 * HIDDEN + ac0);
    #pragma unroll
    for (int i = 0; i < 4; ++i)
        rb[i] = *reinterpret_cast<const bf16x8*>(bsrc + (size_t)br_[i] * HIDDEN + bc_[i]);

    f32x4 acc[4] = {};
    int p = 0;

    for (int k0 = 0; k0 < HIDDEN; k0 += 64) {
        *reinterpret_cast<bf16x8*>(&As[p][ar0 * 72 + ac0]) = ra;
        #pragma unroll
        for (int i = 0; i < 4; ++i)
            *reinterpret_cast<bf16x8*>(&Bs[p][br_[i] * 72 + bc_[i]]) = rb[i];
        __syncthreads();

        if (k0 + 64 < HIDDEN) {
            ra = *reinterpret_cast<const bf16x8*>(asrc + (size_t)ar0 * HIDDEN + k0 + 64 + ac0);
            #pragma unroll
            for (int i = 0; i < 4; ++i)
                rb[i] = *reinterpret_cast<const bf16x8*>(bsrc + (size_t)br_[i] * HIDDEN + k0 + 64 + bc_[i]);
        }

        #pragma unroll
        for (int kh = 0; kh < 2; ++kh) {
            bf16x8 af, bfr[4];
            af = *reinterpret_cast<const bf16x8*>(&As[p][(wr * 16 + ml) * 72 + kh * 32 + quad * 8]);
            #pragma unroll
            for (int ct = 0; ct < 4; ++ct)
                bfr[ct] = *reinterpret_cast<const bf16x8*>(&Bs[p][(wc * 64 + ct * 16 + ml) * 72 + kh * 32 + quad * 8]);
            #pragma unroll
            for (int ct = 0; ct < 4; ++ct)
                acc[ct] = __builtin_amdgcn_mfma_f32_16x16x32_bf16(af, bfr[ct], acc[ct], 0, 0, 0);
        }
        p ^= 1;
    }

    #pragma unroll
    for (int ct = 0; ct < 4; ++ct) {
        int c = col0 + wc * 64 + ct * 16 + ml;
        float bvv = bptr[c];
        #pragma unroll
        for (int reg = 0; reg < 4; ++reg) {
            int R = mt * 32 + wr * 16 + quad * 4 + reg;
            obase[(size_t)R * HIDDEN + c] = __float2bfloat16(acc[ct][reg] + bvv);
        }
    }
}

// ---------------------------------------------------------------------------
// Phase A: token-token attention. 384 blocks x 128 threads (bh x 32-row
// quarter; was 192 x 256 which left 64 CUs idle). V^T staged via coalesced
// u32 row reads + packed LDS transpose writes; qt==0 block spills V^T to ws.
// ---------------------------------------------------------------------------
__global__ __launch_bounds__(128) void attn_tt_kernel(
    const bf16* __restrict__ Qw, const bf16* __restrict__ Kw,
    const bf16* __restrict__ Vw, const float* __restrict__ tmask,
    bf16* __restrict__ ctx_tt, float* __restrict__ m_tt, float* __restrict__ d_tt,
    uint32_t* __restrict__ Vt_g)
{
    __shared__ __align__(16) uint32_t KldsW[128 * 36];
    __shared__ __align__(16) uint32_t VtW[64 * 68];
    __shared__ __align__(16) uint32_t PW[2][16 * 68];
    __shared__ float bias_s[128];

    int bh = blockIdx.x >> 2;
    int qt = blockIdx.x & 3;
    int b = bh / NH, h = bh % NH;
    int tid = threadIdx.x;
    int lane = tid & 63, wv = tid >> 6;          // wv 0..1
    int ml = lane & 15, quad = lane >> 4;

    for (int i = tid; i < 128 * 32; i += 128) {
        int s = i >> 5, w = i & 31;
        KldsW[s * 36 + w] =
            reinterpret_cast<const uint32_t*>(Kw + (size_t)(b * SS + s) * HIDDEN + h * HD)[w];
    }
    #pragma unroll
    for (int c = 0; c < 16; ++c) {
        int g = c * 128 + tid;             // 0..2047
        int s2 = g >> 5, dw = g & 31;
        const uint32_t* v0 = reinterpret_cast<const uint32_t*>(Vw + (size_t)(b * SS + 2 * s2) * HIDDEN + h * HD);
        const uint32_t* v1 = reinterpret_cast<const uint32_t*>(Vw + (size_t)(b * SS + 2 * s2 + 1) * HIDDEN + h * HD);
        uint32_t a = v0[dw], bb = v1[dw];
        VtW[(2 * dw) * 68 + s2]     = (a & 0xffffu) | ((bb & 0xffffu) << 16);
        VtW[(2 * dw + 1) * 68 + s2] = (a >> 16) | (bb & 0xffff0000u);
    }
    if (tid < 128)
        bias_s[tid] = (1.0f - tmask[b * SS + tid]) * -10000.0f;
    __syncthreads();

    if (qt == 0) {
        uint32_t* vg = Vt_g + (size_t)bh * 4096;
        #pragma unroll
        for (int c = 0; c < 32; ++c) {
            int g = c * 128 + tid;
            vg[g] = VtW[(g >> 6) * 68 + (g & 63)];
        }
    }

    const bf16* Klb = reinterpret_cast<const bf16*>(KldsW);
    const bf16* Vtb = reinterpret_cast<const bf16*>(VtW);
    const bf16* Pb  = reinterpret_cast<const bf16*>(PW[wv]);

    int qr = qt * 32 + wv * 16 + ml;
    const bf16* qp = Qw + (size_t)(b * SS + qr) * HIDDEN + h * HD + quad * 8;
    bf16x8 a0 = *reinterpret_cast<const bf16x8*>(qp);
    bf16x8 a1 = *reinterpret_cast<const bf16x8*>(qp + 32);

    f32x4 sc[8];
    #pragma unroll
    for (int ct = 0; ct < 8; ++ct) {
        const bf16* kp = Klb + (ct * 16 + ml) * 72 + quad * 8;
        bf16x8 b0 = *reinterpret_cast<const bf16x8*>(kp);
        bf16x8 b1 = *reinterpret_cast<const bf16x8*>(kp + 32);
        f32x4 z = {0.f, 0.f, 0.f, 0.f};
        z = __builtin_amdgcn_mfma_f32_16x16x32_bf16(a0, b0, z, 0, 0, 0);
        z = __builtin_amdgcn_mfma_f32_16x16x32_bf16(a1, b1, z, 0, 0, 0);
        sc[ct] = z;
    }

    float mx[4] = {-1e30f, -1e30f, -1e30f, -1e30f};
    #pragma unroll
    for (int ct = 0; ct < 8; ++ct) {
        float bc = bias_s[ct * 16 + ml];
        #pragma unroll
        for (int reg = 0; reg < 4; ++reg) {
            float v = sc[ct][reg] * 0.125f + bc;
            sc[ct][reg] = v;
            mx[reg] = fmaxf(mx[reg], v);
        }
    }
    #pragma unroll
    for (int reg = 0; reg < 4; ++reg)
        #pragma unroll
        for (int off = 1; off < 16; off <<= 1)
            mx[reg] = fmaxf(mx[reg], __shfl_xor(mx[reg], off));

    float Zs[4] = {0.f, 0.f, 0.f, 0.f};
    #pragma unroll
    for (int ct = 0; ct < 8; ++ct) {
        #pragma unroll
        for (int reg = 0; reg < 4; ++reg) {
            float e = __expf(sc[ct][reg] - mx[reg]);
            sc[ct][reg] = e;
            Zs[reg] += e;
        }
    }
    #pragma unroll
    for (int reg = 0; reg < 4; ++reg)
        #pragma unroll
        for (int off = 1; off < 16; off <<= 1)
            Zs[reg] += __shfl_xor(Zs[reg], off);

    #pragma unroll
    for (int reg = 0; reg < 4; ++reg) {
        int gr = bh * 128 + qt * 32 + wv * 16 + quad * 4 + reg;
        if (ml == 0) { m_tt[gr] = mx[reg]; d_tt[gr] = Zs[reg]; }
    }

    #pragma unroll
    for (int ct = 0; ct < 8; ++ct) {
        #pragma unroll
        for (int reg = 0; reg < 4; ++reg) {
            float e = sc[ct][reg];
            float ep = __shfl_xor(e, 1);
            if ((ml & 1) == 0)
                PW[wv][(quad * 4 + reg) * 68 + ct * 8 + (ml >> 1)] =
                    (uint32_t)b16bits(e) | ((uint32_t)b16bits(ep) << 16);
        }
    }

    float rZ[4];
    #pragma unroll
    for (int reg = 0; reg < 4; ++reg) rZ[reg] = 1.0f / Zs[reg];

    #pragma unroll
    for (int ct4 = 0; ct4 < 4; ++ct4) {
        f32x4 acc = {0.f, 0.f, 0.f, 0.f};
        #pragma unroll
        for (int ks = 0; ks < 4; ++ks) {
            bf16x8 ap = *reinterpret_cast<const bf16x8*>(Pb + ml * 136 + ks * 32 + quad * 8);
            bf16x8 bp = *reinterpret_cast<const bf16x8*>(Vtb + (ct4 * 16 + ml) * 136 + ks * 32 + quad * 8);
            acc = __builtin_amdgcn_mfma_f32_16x16x32_bf16(ap, bp, acc, 0, 0, 0);
        }
        #pragma unroll
        for (int reg = 0; reg < 4; ++reg) {
            int gr = bh * 128 + qt * 32 + wv * 16 + quad * 4 + reg;
            ctx_tt[(size_t)gr * 64 + ct4 * 16 + ml] = __float2bfloat16(acc[reg] * rZ[reg]);
        }
    }
}

// ---------------------------------------------------------------------------
// Phase B: per (b,h,label-pair) = 768 blocks. Token V^T staged by a straight
// coalesced copy from Vt_g (built once by phase A); only the 16 label cols
// are transposed here.
// ---------------------------------------------------------------------------
__global__ __launch_bounds__(256) void attn_merge_kernel(
    const bf16* __restrict__ Qw, const bf16* __restrict__ Kw,
    const bf16* __restrict__ Vw, const uint32_t* __restrict__ Vt_g,
    const bf16* __restrict__ ctx_tt, const float* __restrict__ m_tt,
    const float* __restrict__ d_tt,
    const float* __restrict__ tmask, const float* __restrict__ lmask,
    float* __restrict__ out)
{
    __shared__ __align__(16) uint32_t VtW[64 * 84];     // 21504 B
    __shared__ __align__(16) uint32_t PWL[16 * 84];     //  5376 B (wave-3 label P)
    __shared__ __align__(16) uint32_t P2W[4][32 * 8];   //  4096 B (token P, 32rx16c)
    __shared__ float wtab[4][32], itab[4][32];
    __shared__ float mtt_s[128], dtt_s[128], bias_t[128];
    __shared__ float bias_l[16];

    int p = blockIdx.x & 7;
    int h = (blockIdx.x >> 3) % NH;
    int b = blockIdx.x / (8 * NH);
    int l0 = 2 * p, l1 = l0 + 1;
    int bh = b * NH + h;
    int tid = threadIdx.x;
    int lane = tid & 63, wv = tid >> 6;
    int ml = lane & 15, quad = lane >> 4;
    int hl = lane & 31, hi = lane >> 5;

    {
        const uint32_t* vg = Vt_g + (size_t)bh * 4096;
        #pragma unroll
        for (int c = 0; c < 16; ++c) {
            int g = c * 256 + tid;
            VtW[(g >> 6) * 84 + (g & 63)] = vg[g];
        }
    }
    for (int g = tid; g < 512; g += 256) {
        int d = g >> 3, jj = g & 7;
        int s0 = 128 + 2 * jj, s1 = s0 + 1;
        int r0 = (s0 < 136) ? (1024 + l0 * LS + (s0 - 128)) : (1024 + l1 * LS + (s0 - 136));
        int r1 = (s1 < 136) ? (1024 + l0 * LS + (s1 - 128)) : (1024 + l1 * LS + (s1 - 136));
        uint16_t lo = reinterpret_cast<const uint16_t*>(Vw + (size_t)r0 * HIDDEN + h * HD)[d];
        uint16_t hi2 = reinterpret_cast<const uint16_t*>(Vw + (size_t)r1 * HIDDEN + h * HD)[d];
        VtW[d * 84 + 64 + jj] = (uint32_t)lo | ((uint32_t)hi2 << 16);
    }
    for (int g = tid; g < 512; g += 256)
        VtW[(g >> 3) * 84 + 72 + (g & 7)] = 0;

    if (tid < 128) {
        mtt_s[tid] = m_tt[bh * 128 + tid];
        dtt_s[tid] = d_tt[bh * 128 + tid];
        bias_t[tid] = (1.0f - tmask[b * SS + tid]) * -10000.0f;
    }
    if (tid < 16) {
        int labk = (tid < 8) ? (l0 * LS + tid) : (l1 * LS + tid - 8);
        bias_l[tid] = (1.0f - lmask[labk]) * -10000.0f;
    }
    if (tid < 128)
        PWL[(tid >> 3) * 84 + 72 + (tid & 7)] = 0;
    __syncthreads();

    const bf16* Vtb = reinterpret_cast<const bf16*>(VtW);

    int kprow = 1024 + ((ml < 8) ? (l0 * LS + ml) : (l1 * LS + ml - 8));
    const bf16* kpp = Kw + (size_t)kprow * HIDDEN + h * HD + quad * 8;
    bf16x8 kb0 = *reinterpret_cast<const bf16x8*>(kpp);
    bf16x8 kb1 = *reinterpret_cast<const bf16x8*>(kpp + 32);

    if (wv < 3) {
        const bf16* P2b = reinterpret_cast<const bf16*>(P2W[wv]);
        for (int rt = wv; rt < 8; rt += 3) {
            int tq = rt * 16 + ml;
            const bf16* qp = Qw + (size_t)(b * SS + tq) * HIDDEN + h * HD + quad * 8;
            bf16x8 a0 = *reinterpret_cast<const bf16x8*>(qp);
            bf16x8 a1 = *reinterpret_cast<const bf16x8*>(qp + 32);

            f32x4 z = {0.f, 0.f, 0.f, 0.f};
            z = __builtin_amdgcn_mfma_f32_16x16x32_bf16(a0, kb0, z, 0, 0, 0);
            z = __builtin_amdgcn_mfma_f32_16x16x32_bf16(a1, kb1, z, 0, 0, 0);

            #pragma unroll
            for (int reg = 0; reg < 4; ++reg) {
                int trow = quad * 4 + reg;
                float s = z[reg] * 0.125f + bias_l[ml];
                float m = s;
                m = fmaxf(m, __shfl_xor(m, 1));
                m = fmaxf(m, __shfl_xor(m, 2));
                m = fmaxf(m, __shfl_xor(m, 4));
                float mtt = mtt_s[rt * 16 + trow], dtt = dtt_s[rt * 16 + trow];
                float m_new = fmaxf(mtt, m);
                float e = __expf(s - m_new);
                float dh = e;
                dh += __shfl_xor(dh, 1);
                dh += __shfl_xor(dh, 2);
                dh += __shfl_xor(dh, 4);
                float alpha = __expf(mtt - m_new);
                float w = alpha * dtt;
                float inv = 1.0f / (w + dh);
                if (ml == 0) { wtab[wv][trow] = w;      itab[wv][trow] = inv; }
                if (ml == 8) { wtab[wv][16 + trow] = w; itab[wv][16 + trow] = inv; }
                float ep = __shfl_xor(e, 1);
                if ((ml & 1) == 0) {
                    uint32_t pk = (uint32_t)b16bits(e) | ((uint32_t)b16bits(ep) << 16);
                    P2W[wv][trow * 8 + (ml >> 1)]        = (ml < 8) ? pk : 0u;
                    P2W[wv][(16 + trow) * 8 + (ml >> 1)] = (ml < 8) ? 0u : pk;
                }
            }

            bf16x8 ap  = *reinterpret_cast<const bf16x8*>(P2b + hl * 16 + hi * 8);
            bf16x8 bv0 = *reinterpret_cast<const bf16x8*>(Vtb + hl * 168 + 128 + hi * 8);
            bf16x8 bv1 = *reinterpret_cast<const bf16x8*>(Vtb + (32 + hl) * 168 + 128 + hi * 8);
            f32x16 c0 = {}, c1 = {};
            c0 = __builtin_amdgcn_mfma_f32_32x32x16_bf16(ap, bv0, c0, 0, 0, 0);
            c1 = __builtin_amdgcn_mfma_f32_32x32x16_bf16(ap, bv1, c1, 0, 0, 0);

            float cv0[8], cv1[8];
            #pragma unroll
            for (int reg = 0; reg < 8; ++reg) {
                int row = (reg & 3) + 8 * (reg >> 2) + 4 * hi;
                const bf16* cp = ctx_tt + (size_t)(bh * 128 + rt * 16 + row) * 64;
                cv0[reg] = tof(cp[hl]);
                cv1[reg] = tof(cp[32 + hl]);
            }
            #pragma unroll
            for (int reg = 0; reg < 16; ++reg) {
                int row = (reg & 3) + 8 * (reg >> 2) + 4 * hi;
                int trow = row & 15;
                int lsel = (row < 16) ? l0 : l1;
                float w = wtab[wv][row], inv = itab[wv][row];
                float c0v = (reg < 8) ? cv0[reg] : cv0[reg - 8];
                float c1v = (reg < 8) ? cv1[reg] : cv1[reg - 8];
                size_t ob = (((size_t)b * TT + rt * 16 + trow) * LL + lsel) * HIDDEN + h * HD;
                out[ob + hl]      = (w * c0v + c0[reg]) * inv;
                out[ob + 32 + hl] = (w * c1v + c1[reg]) * inv;
            }
        }
    } else {
        const bf16* Pb = reinterpret_cast<const bf16*>(PWL);
        int qrow = 1024 + ((ml < 8) ? (l0 * LS + ml) : (l1 * LS + ml - 8));
        const bf16* qp = Qw + (size_t)qrow * HIDDEN + h * HD + quad * 8;
        bf16x8 a0 = *reinterpret_cast<const bf16x8*>(qp);
        bf16x8 a1 = *reinterpret_cast<const bf16x8*>(qp + 32);

        f32x4 sc[9];
        #pragma unroll
        for (int ct = 0; ct < 9; ++ct) {
            bf16x8 b0, b1;
            if (ct < 8) {
                const bf16* kp = Kw + (size_t)(b * SS + ct * 16 + ml) * HIDDEN + h * HD + quad * 8;
                b0 = *reinterpret_cast<const bf16x8*>(kp);
                b1 = *reinterpret_cast<const bf16x8*>(kp + 32);
            } else { b0 = kb0; b1 = kb1; }
            f32x4 zz = {0.f, 0.f, 0.f, 0.f};
            zz = __builtin_amdgcn_mfma_f32_16x16x32_bf16(a0, b0, zz, 0, 0, 0);
            zz = __builtin_amdgcn_mfma_f32_16x16x32_bf16(a1, b1, zz, 0, 0, 0);
            sc[ct] = zz;
        }

        float mx[4] = {-1e30f, -1e30f, -1e30f, -1e30f};
        #pragma unroll
        for (int ct = 0; ct < 9; ++ct) {
            #pragma unroll
            for (int reg = 0; reg < 4; ++reg) {
                int rq = quad * 4 + reg;
                float bc = (ct < 8) ? bias_t[ct * 16 + ml]
                                    : (((rq < 8) != (ml < 8)) ? -1e30f : bias_l[ml]);
                float v = sc[ct][reg] * 0.125f + bc;
                sc[ct][reg] = v;
                mx[reg] = fmaxf(mx[reg], v);
            }
        }
        #pragma unroll
        for (int reg = 0; reg < 4; ++reg)
            #pragma unroll
            for (int off = 1; off < 16; off <<= 1)
                mx[reg] = fmaxf(mx[reg], __shfl_xor(mx[reg], off));

        float Zs[4] = {0.f, 0.f, 0.f, 0.f};
        #pragma unroll
        for (int ct = 0; ct < 9; ++ct) {
            #pragma unroll
            for (int reg = 0; reg < 4; ++reg) {
                float e = __expf(sc[ct][reg] - mx[reg]);
                sc[ct][reg] = e;
                Zs[reg] += e;
            }
        }
        #pragma unroll
        for (int reg = 0; reg < 4; ++reg)
            #pragma unroll
            for (int off = 1; off < 16; off <<= 1)
                Zs[reg] += __shfl_xor(Zs[reg], off);
        float zi[4];
        #pragma unroll
        for (int reg = 0; reg < 4; ++reg) zi[reg] = 1.0f / Zs[reg];

        #pragma unroll
        for (int ct = 0; ct < 9; ++ct) {
            #pragma unroll
            for (int reg = 0; reg < 4; ++reg) {
                float e = sc[ct][reg];
                float ep = __shfl_xor(e, 1);
                if ((ml & 1) == 0)
                    PWL[(quad * 4 + reg) * 84 + ct * 8 + (ml >> 1)] =
                        (uint32_t)b16bits(e) | ((uint32_t)b16bits(ep) << 16);
            }
        }

        #pragma unroll
        for (int ct4 = 0; ct4 < 4; ++ct4) {
            f32x4 acc = {0.f, 0.f, 0.f, 0.f};
            #pragma unroll
            for (int ks = 0; ks < 5; ++ks) {
                bf16x8 ap = *reinterpret_cast<const bf16x8*>(Pb + ml * 168 + ks * 32 + quad * 8);
                bf16x8 bp = *reinterpret_cast<const bf16x8*>(Vtb + (ct4 * 16 + ml) * 168 + ks * 32 + quad * 8);
                acc = __builtin_amdgcn_mfma_f32_16x16x32_bf16(ap, bp, acc, 0, 0, 0);
            }
            #pragma unroll
            for (int reg = 0; reg < 4; ++reg) {
                int rq = quad * 4 + reg;
                int l = (rq < 8) ? l0 : l1;
                int t = SS + (rq & 7);
                out[(((size_t)b * TT + t) * LL + l) * HIDDEN + h * HD + ct4 * 16 + ml] =
                    acc[reg] * zi[reg];
            }
        }
    }
}

extern "C" void kernel_launch(void* const* d_in, const int* in_sizes, int n_in,
                              void* d_out, int out_size, void* d_ws, size_t ws_size,
                              hipStream_t stream)
{
    const float* tok   = (const float*)d_in[0];
    const float* lab   = (const float*)d_in[1];
    const float* tmask = (const float*)d_in[2];
    const float* lmask = (const float*)d_in[3];
    const float* Wq    = (const float*)d_in[4];
    const float* bq    = (const float*)d_in[5];
    const float* Wk    = (const float*)d_in[6];
    const float* bk    = (const float*)d_in[7];
    const float* Wv    = (const float*)d_in[8];
    const float* bv    = (const float*)d_in[9];

    // ws: Q/K/V bf16 (5,308,416) + ctx_tt bf16 (1,572,864) + m/d f32 (98,304)
    //     + Vt_g u32 (1,572,864) + Xb bf16 (1,769,472) + Wb bf16 (3,538,944)
    //     = 13,860,864 B.
    bf16* Qw = (bf16*)d_ws;
    bf16* Kw = Qw + (size_t)NROWS * HIDDEN;
    bf16* Vw = Kw + (size_t)NROWS * HIDDEN;
    bf16* ctx = Vw + (size_t)NROWS * HIDDEN;
    float* m_tt = (float*)(ctx + (size_t)BH * 128 * 64);
    float* d_tt = m_tt + BH * 128;
    uint32_t* Vt_g = (uint32_t*)(d_tt + BH * 128);
    uint16_t* Xb = (uint16_t*)(Vt_g + (size_t)BH * 4096);
    uint16_t* Wb = Xb + (size_t)NROWS * HIDDEN;

    cast_kernel<<<dim3(2592), 256, 0, stream>>>(tok, lab, Wq, Wk, Wv, Xb, Wb);
    qkv_kernel<<<dim3(36 * 18), 256, 0, stream>>>(
        Xb, Wb, bq, bk, bv, Qw, Kw, Vw);
    attn_tt_kernel<<<dim3(BH * 4), 128, 0, stream>>>(
        Qw, Kw, Vw, tmask, ctx, m_tt, d_tt, Vt_g);
    attn_merge_kernel<<<dim3(BB * NH * 8), 256, 0, stream>>>(
        Qw, Kw, Vw, Vt_g, ctx, m_tt, d_tt, tmask, lmask, (float*)d_out);
}

// Round 5
// 129.210 us; speedup vs baseline: 1.0342x; 1.0290x over previous
//
#include <hip/hip_runtime.h>
#include <hip/hip_bf16.h>
#include <stdint.h>

#define HIDDEN 768
#define NH 12
#define HD 64
#define BB 8
#define SS 128
#define LL 16
#define LS 8
#define TT 136            // SS + LS
#define NROWS 1152        // BB*SS + LL*LS rows of the unique-row Xcat
#define BH (BB * NH)      // 96

typedef __attribute__((ext_vector_type(8))) short bf16x8;
typedef __attribute__((ext_vector_type(4))) float f32x4;
typedef __attribute__((ext_vector_type(16))) float f32x16;
typedef __hip_bfloat16 bf16;

__device__ inline float tof(bf16 x) { return __bfloat162float(x); }
__device__ inline uint16_t b16bits(float f) {
    bf16 h = __float2bfloat16(f);
    union { bf16 h; uint16_t u; } u; u.h = h; return u.u;
}

// ---------------------------------------------------------------------------
// One-shot f32 -> bf16 cast of X ([tok;lab] -> Xb[1152][768]) and W
// ([Wq;Wk;Wv] -> Wb[2304][768]).
// ---------------------------------------------------------------------------
#define TOK_V4 196608     // 8*128*768/4
#define XB_V4  221184     // + 16*8*768/4
#define W_V4   147456     // 768*768/4
__global__ __launch_bounds__(256) void cast_kernel(
    const float* __restrict__ tok, const float* __restrict__ lab,
    const float* __restrict__ Wq, const float* __restrict__ Wk,
    const float* __restrict__ Wv,
    uint16_t* __restrict__ Xb, uint16_t* __restrict__ Wb)
{
    int g = blockIdx.x * 256 + threadIdx.x;
    float4 v;
    ushort4* d;
    if (g < XB_V4) {
        v = (g < TOK_V4) ? reinterpret_cast<const float4*>(tok)[g]
                         : reinterpret_cast<const float4*>(lab)[g - TOK_V4];
        d = reinterpret_cast<ushort4*>(Xb) + g;
    } else {
        int w = g - XB_V4;
        v = (w < W_V4)     ? reinterpret_cast<const float4*>(Wq)[w]
          : (w < 2 * W_V4) ? reinterpret_cast<const float4*>(Wk)[w - W_V4]
                           : reinterpret_cast<const float4*>(Wv)[w - 2 * W_V4];
        d = reinterpret_cast<ushort4*>(Wb) + w;
    }
    ushort4 h;
    h.x = b16bits(v.x); h.y = b16bits(v.y); h.z = b16bits(v.z); h.w = b16bits(v.w);
    *d = h;
}

// ---------------------------------------------------------------------------
// QKV projection: C[1152,2304] = Xb @ Wb^T + bias, bf16 inputs. 64x128 tile,
// BK=64, double-buffered LDS + register prefetch. (Best measured config:
// 324 blocks; 32x128 retile and merge-pairing variants both regressed.)
// ---------------------------------------------------------------------------
__global__ __launch_bounds__(256) void qkv_kernel(
    const uint16_t* __restrict__ Xb, const uint16_t* __restrict__ Wb,
    const float* __restrict__ bq, const float* __restrict__ bk,
    const float* __restrict__ bv,
    bf16* __restrict__ Qw, bf16* __restrict__ Kw, bf16* __restrict__ Vw)
{
    __shared__ __align__(16) uint16_t As[2][64 * 72];    // 2 x  9216 B
    __shared__ __align__(16) uint16_t Bs[2][128 * 72];   // 2 x 18432 B

    int tid = threadIdx.x;
    int lane = tid & 63, wv = tid >> 6;
    int ml = lane & 15, quad = lane >> 4;
    int mt = blockIdx.x / 18, nt = blockIdx.x % 18;
    int wr = wv >> 1, wc = wv & 1;

    int mat = nt / 6;
    int col0 = (nt % 6) * 128;
    const float* bptr = (mat == 0) ? bq : ((mat == 1) ? bk : bv);
    bf16* obase       = (mat == 0) ? Qw : ((mat == 1) ? Kw : Vw);

    const uint16_t* asrc = Xb + (size_t)mt * 64 * HIDDEN;
    const uint16_t* bsrc = Wb + (size_t)nt * 128 * HIDDEN;

    int ar_[2], ac_[2], br_[4], bc_[4];
    #pragma unroll
    for (int i = 0; i < 2; ++i) { int g = i * 256 + tid; ar_[i] = g >> 3; ac_[i] = (g & 7) * 8; }
    #pragma unroll
    for (int i = 0; i < 4; ++i) { int g = i * 256 + tid; br_[i] = g >> 3; bc_[i] = (g & 7) * 8; }

    bf16x8 ra[2], rb[4];
    #pragma unroll
    for (int i = 0; i < 2; ++i)
        ra[i] = *reinterpret_cast<const bf16x8*>(asrc + (size_t)ar_[i] * HIDDEN + ac_[i]);
    #pragma unroll
    for (int i = 0; i < 4; ++i)
        rb[i] = *reinterpret_cast<const bf16x8*>(bsrc + (size_t)br_[i] * HIDDEN + bc_[i]);

    f32x4 acc[2][4] = {};
    int p = 0;

    for (int k0 = 0; k0 < HIDDEN; k0 += 64) {
        #pragma unroll
        for (int i = 0; i < 2; ++i)
            *reinterpret_cast<bf16x8*>(&As[p][ar_[i] * 72 + ac_[i]]) = ra[i];
        #pragma unroll
        for (int i = 0; i < 4; ++i)
            *reinterpret_cast<bf16x8*>(&Bs[p][br_[i] * 72 + bc_[i]]) = rb[i];
        __syncthreads();

        if (k0 + 64 < HIDDEN) {
            #pragma unroll
            for (int i = 0; i < 2; ++i)
                ra[i] = *reinterpret_cast<const bf16x8*>(asrc + (size_t)ar_[i] * HIDDEN + k0 + 64 + ac_[i]);
            #pragma unroll
            for (int i = 0; i < 4; ++i)
                rb[i] = *reinterpret_cast<const bf16x8*>(bsrc + (size_t)br_[i] * HIDDEN + k0 + 64 + bc_[i]);
        }

        #pragma unroll
        for (int kh = 0; kh < 2; ++kh) {
            bf16x8 af[2], bfr[4];
            #pragma unroll
            for (int rt = 0; rt < 2; ++rt)
                af[rt] = *reinterpret_cast<const bf16x8*>(&As[p][(wr * 32 + rt * 16 + ml) * 72 + kh * 32 + quad * 8]);
            #pragma unroll
            for (int ct = 0; ct < 4; ++ct)
                bfr[ct] = *reinterpret_cast<const bf16x8*>(&Bs[p][(wc * 64 + ct * 16 + ml) * 72 + kh * 32 + quad * 8]);
            #pragma unroll
            for (int rt = 0; rt < 2; ++rt)
                #pragma unroll
                for (int ct = 0; ct < 4; ++ct)
                    acc[rt][ct] = __builtin_amdgcn_mfma_f32_16x16x32_bf16(af[rt], bfr[ct], acc[rt][ct], 0, 0, 0);
        }
        p ^= 1;
    }

    #pragma unroll
    for (int ct = 0; ct < 4; ++ct) {
        int c = col0 + wc * 64 + ct * 16 + ml;
        float bvv = bptr[c];
        #pragma unroll
        for (int rt = 0; rt < 2; ++rt) {
            #pragma unroll
            for (int reg = 0; reg < 4; ++reg) {
                int R = mt * 64 + wr * 32 + rt * 16 + quad * 4 + reg;
                obase[(size_t)R * HIDDEN + c] = __float2bfloat16(acc[rt][ct][reg] + bvv);
            }
        }
    }
}

// ---------------------------------------------------------------------------
// Phase A: token-token attention once per (b,h). V^T staged via coalesced
// u32 row reads + packed LDS transpose writes; hf==0 block spills V^T to ws.
// ---------------------------------------------------------------------------
__global__ __launch_bounds__(256) void attn_tt_kernel(
    const bf16* __restrict__ Qw, const bf16* __restrict__ Kw,
    const bf16* __restrict__ Vw, const float* __restrict__ tmask,
    bf16* __restrict__ ctx_tt, float* __restrict__ m_tt, float* __restrict__ d_tt,
    uint32_t* __restrict__ Vt_g)
{
    __shared__ __align__(16) uint32_t KldsW[128 * 36];
    __shared__ __align__(16) uint32_t VtW[64 * 68];
    __shared__ __align__(16) uint32_t PW[4][16 * 68];
    __shared__ float bias_s[128];

    int bh = blockIdx.x >> 1;
    int hf = blockIdx.x & 1;
    int b = bh / NH, h = bh % NH;
    int tid = threadIdx.x;
    int lane = tid & 63, wv = tid >> 6;
    int ml = lane & 15, quad = lane >> 4;

    for (int i = tid; i < 128 * 32; i += 256) {
        int s = i >> 5, w = i & 31;
        KldsW[s * 36 + w] =
            reinterpret_cast<const uint32_t*>(Kw + (size_t)(b * SS + s) * HIDDEN + h * HD)[w];
    }
    #pragma unroll
    for (int c = 0; c < 8; ++c) {
        int g = c * 256 + tid;             // 0..2047
        int s2 = g >> 5, dw = g & 31;
        const uint32_t* v0 = reinterpret_cast<const uint32_t*>(Vw + (size_t)(b * SS + 2 * s2) * HIDDEN + h * HD);
        const uint32_t* v1 = reinterpret_cast<const uint32_t*>(Vw + (size_t)(b * SS + 2 * s2 + 1) * HIDDEN + h * HD);
        uint32_t a = v0[dw], bb = v1[dw];
        VtW[(2 * dw) * 68 + s2]     = (a & 0xffffu) | ((bb & 0xffffu) << 16);
        VtW[(2 * dw + 1) * 68 + s2] = (a >> 16) | (bb & 0xffff0000u);
    }
    for (int i = tid; i < 128; i += 256)
        bias_s[i] = (1.0f - tmask[b * SS + i]) * -10000.0f;
    __syncthreads();

    if (hf == 0) {
        uint32_t* vg = Vt_g + (size_t)bh * 4096;
        #pragma unroll
        for (int c = 0; c < 16; ++c) {
            int g = c * 256 + tid;
            vg[g] = VtW[(g >> 6) * 68 + (g & 63)];
        }
    }

    const bf16* Klb = reinterpret_cast<const bf16*>(KldsW);
    const bf16* Vtb = reinterpret_cast<const bf16*>(VtW);
    const bf16* Pb  = reinterpret_cast<const bf16*>(PW[wv]);

    int qr = hf * 64 + wv * 16 + ml;
    const bf16* qp = Qw + (size_t)(b * SS + qr) * HIDDEN + h * HD + quad * 8;
    bf16x8 a0 = *reinterpret_cast<const bf16x8*>(qp);
    bf16x8 a1 = *reinterpret_cast<const bf16x8*>(qp + 32);

    f32x4 sc[8];
    #pragma unroll
    for (int ct = 0; ct < 8; ++ct) {
        const bf16* kp = Klb + (ct * 16 + ml) * 72 + quad * 8;
        bf16x8 b0 = *reinterpret_cast<const bf16x8*>(kp);
        bf16x8 b1 = *reinterpret_cast<const bf16x8*>(kp + 32);
        f32x4 z = {0.f, 0.f, 0.f, 0.f};
        z = __builtin_amdgcn_mfma_f32_16x16x32_bf16(a0, b0, z, 0, 0, 0);
        z = __builtin_amdgcn_mfma_f32_16x16x32_bf16(a1, b1, z, 0, 0, 0);
        sc[ct] = z;
    }

    float mx[4] = {-1e30f, -1e30f, -1e30f, -1e30f};
    #pragma unroll
    for (int ct = 0; ct < 8; ++ct) {
        float bc = bias_s[ct * 16 + ml];
        #pragma unroll
        for (int reg = 0; reg < 4; ++reg) {
            float v = sc[ct][reg] * 0.125f + bc;
            sc[ct][reg] = v;
            mx[reg] = fmaxf(mx[reg], v);
        }
    }
    #pragma unroll
    for (int reg = 0; reg < 4; ++reg)
        #pragma unroll
        for (int off = 1; off < 16; off <<= 1)
            mx[reg] = fmaxf(mx[reg], __shfl_xor(mx[reg], off));

    float Zs[4] = {0.f, 0.f, 0.f, 0.f};
    #pragma unroll
    for (int ct = 0; ct < 8; ++ct) {
        #pragma unroll
        for (int reg = 0; reg < 4; ++reg) {
            float e = __expf(sc[ct][reg] - mx[reg]);
            sc[ct][reg] = e;
            Zs[reg] += e;
        }
    }
    #pragma unroll
    for (int reg = 0; reg < 4; ++reg)
        #pragma unroll
        for (int off = 1; off < 16; off <<= 1)
            Zs[reg] += __shfl_xor(Zs[reg], off);

    #pragma unroll
    for (int reg = 0; reg < 4; ++reg) {
        int gr = bh * 128 + hf * 64 + wv * 16 + quad * 4 + reg;
        if (ml == 0) { m_tt[gr] = mx[reg]; d_tt[gr] = Zs[reg]; }
    }

    #pragma unroll
    for (int ct = 0; ct < 8; ++ct) {
        #pragma unroll
        for (int reg = 0; reg < 4; ++reg) {
            float e = sc[ct][reg];
            float ep = __shfl_xor(e, 1);
            if ((ml & 1) == 0)
                PW[wv][(quad * 4 + reg) * 68 + ct * 8 + (ml >> 1)] =
                    (uint32_t)b16bits(e) | ((uint32_t)b16bits(ep) << 16);
        }
    }

    float rZ[4];
    #pragma unroll
    for (int reg = 0; reg < 4; ++reg) rZ[reg] = 1.0f / Zs[reg];

    #pragma unroll
    for (int ct4 = 0; ct4 < 4; ++ct4) {
        f32x4 acc = {0.f, 0.f, 0.f, 0.f};
        #pragma unroll
        for (int ks = 0; ks < 4; ++ks) {
            bf16x8 ap = *reinterpret_cast<const bf16x8*>(Pb + ml * 136 + ks * 32 + quad * 8);
            bf16x8 bp = *reinterpret_cast<const bf16x8*>(Vtb + (ct4 * 16 + ml) * 136 + ks * 32 + quad * 8);
            acc = __builtin_amdgcn_mfma_f32_16x16x32_bf16(ap, bp, acc, 0, 0, 0);
        }
        #pragma unroll
        for (int reg = 0; reg < 4; ++reg) {
            int gr = bh * 128 + hf * 64 + wv * 16 + quad * 4 + reg;
            ctx_tt[(size_t)gr * 64 + ct4 * 16 + ml] = __float2bfloat16(acc[reg] * rZ[reg]);
        }
    }
}

// ---------------------------------------------------------------------------
// Phase B: per (b,h,label-pair) = 768 blocks. Token V^T staged by a straight
// coalesced copy from Vt_g (built once by phase A); only the 16 label cols
// are transposed here.
// ---------------------------------------------------------------------------
__global__ __launch_bounds__(256) void attn_merge_kernel(
    const bf16* __restrict__ Qw, const bf16* __restrict__ Kw,
    const bf16* __restrict__ Vw, const uint32_t* __restrict__ Vt_g,
    const bf16* __restrict__ ctx_tt, const float* __restrict__ m_tt,
    const float* __restrict__ d_tt,
    const float* __restrict__ tmask, const float* __restrict__ lmask,
    float* __restrict__ out)
{
    __shared__ __align__(16) uint32_t VtW[64 * 84];     // 21504 B
    __shared__ __align__(16) uint32_t PWL[16 * 84];     //  5376 B (wave-3 label P)
    __shared__ __align__(16) uint32_t P2W[4][32 * 8];   //  4096 B (token P, 32rx16c)
    __shared__ float wtab[4][32], itab[4][32];
    __shared__ float mtt_s[128], dtt_s[128], bias_t[128];
    __shared__ float bias_l[16];

    int p = blockIdx.x & 7;
    int h = (blockIdx.x >> 3) % NH;
    int b = blockIdx.x / (8 * NH);
    int l0 = 2 * p, l1 = l0 + 1;
    int bh = b * NH + h;
    int tid = threadIdx.x;
    int lane = tid & 63, wv = tid >> 6;
    int ml = lane & 15, quad = lane >> 4;
    int hl = lane & 31, hi = lane >> 5;

    {
        const uint32_t* vg = Vt_g + (size_t)bh * 4096;
        #pragma unroll
        for (int c = 0; c < 16; ++c) {
            int g = c * 256 + tid;
            VtW[(g >> 6) * 84 + (g & 63)] = vg[g];
        }
    }
    for (int g = tid; g < 512; g += 256) {
        int d = g >> 3, jj = g & 7;
        int s0 = 128 + 2 * jj, s1 = s0 + 1;
        int r0 = (s0 < 136) ? (1024 + l0 * LS + (s0 - 128)) : (1024 + l1 * LS + (s0 - 136));
        int r1 = (s1 < 136) ? (1024 + l0 * LS + (s1 - 128)) : (1024 + l1 * LS + (s1 - 136));
        uint16_t lo = reinterpret_cast<const uint16_t*>(Vw + (size_t)r0 * HIDDEN + h * HD)[d];
        uint16_t hi2 = reinterpret_cast<const uint16_t*>(Vw + (size_t)r1 * HIDDEN + h * HD)[d];
        VtW[d * 84 + 64 + jj] = (uint32_t)lo | ((uint32_t)hi2 << 16);
    }
    for (int g = tid; g < 512; g += 256)
        VtW[(g >> 3) * 84 + 72 + (g & 7)] = 0;

    if (tid < 128) {
        mtt_s[tid] = m_tt[bh * 128 + tid];
        dtt_s[tid] = d_tt[bh * 128 + tid];
        bias_t[tid] = (1.0f - tmask[b * SS + tid]) * -10000.0f;
    }
    if (tid < 16) {
        int labk = (tid < 8) ? (l0 * LS + tid) : (l1 * LS + tid - 8);
        bias_l[tid] = (1.0f - lmask[labk]) * -10000.0f;
    }
    if (tid < 128)
        PWL[(tid >> 3) * 84 + 72 + (tid & 7)] = 0;
    __syncthreads();

    const bf16* Vtb = reinterpret_cast<const bf16*>(VtW);

    int kprow = 1024 + ((ml < 8) ? (l0 * LS + ml) : (l1 * LS + ml - 8));
    const bf16* kpp = Kw + (size_t)kprow * HIDDEN + h * HD + quad * 8;
    bf16x8 kb0 = *reinterpret_cast<const bf16x8*>(kpp);
    bf16x8 kb1 = *reinterpret_cast<const bf16x8*>(kpp + 32);

    if (wv < 3) {
        const bf16* P2b = reinterpret_cast<const bf16*>(P2W[wv]);
        for (int rt = wv; rt < 8; rt += 3) {
            int tq = rt * 16 + ml;
            const bf16* qp = Qw + (size_t)(b * SS + tq) * HIDDEN + h * HD + quad * 8;
            bf16x8 a0 = *reinterpret_cast<const bf16x8*>(qp);
            bf16x8 a1 = *reinterpret_cast<const bf16x8*>(qp + 32);

            f32x4 z = {0.f, 0.f, 0.f, 0.f};
            z = __builtin_amdgcn_mfma_f32_16x16x32_bf16(a0, kb0, z, 0, 0, 0);
            z = __builtin_amdgcn_mfma_f32_16x16x32_bf16(a1, kb1, z, 0, 0, 0);

            #pragma unroll
            for (int reg = 0; reg < 4; ++reg) {
                int trow = quad * 4 + reg;
                float s = z[reg] * 0.125f + bias_l[ml];
                float m = s;
                m = fmaxf(m, __shfl_xor(m, 1));
                m = fmaxf(m, __shfl_xor(m, 2));
                m = fmaxf(m, __shfl_xor(m, 4));
                float mtt = mtt_s[rt * 16 + trow], dtt = dtt_s[rt * 16 + trow];
                float m_new = fmaxf(mtt, m);
                float e = __expf(s - m_new);
                float dh = e;
                dh += __shfl_xor(dh, 1);
                dh += __shfl_xor(dh, 2);
                dh += __shfl_xor(dh, 4);
                float alpha = __expf(mtt - m_new);
                float w = alpha * dtt;
                float inv = 1.0f / (w + dh);
                if (ml == 0) { wtab[wv][trow] = w;      itab[wv][trow] = inv; }
                if (ml == 8) { wtab[wv][16 + trow] = w; itab[wv][16 + trow] = inv; }
                float ep = __shfl_xor(e, 1);
                if ((ml & 1) == 0) {
                    uint32_t pk = (uint32_t)b16bits(e) | ((uint32_t)b16bits(ep) << 16);
                    P2W[wv][trow * 8 + (ml >> 1)]        = (ml < 8) ? pk : 0u;
                    P2W[wv][(16 + trow) * 8 + (ml >> 1)] = (ml < 8) ? 0u : pk;
                }
            }

            bf16x8 ap  = *reinterpret_cast<const bf16x8*>(P2b + hl * 16 + hi * 8);
            bf16x8 bv0 = *reinterpret_cast<const bf16x8*>(Vtb + hl * 168 + 128 + hi * 8);
            bf16x8 bv1 = *reinterpret_cast<const bf16x8*>(Vtb + (32 + hl) * 168 + 128 + hi * 8);
            f32x16 c0 = {}, c1 = {};
            c0 = __builtin_amdgcn_mfma_f32_32x32x16_bf16(ap, bv0, c0, 0, 0, 0);
            c1 = __builtin_amdgcn_mfma_f32_32x32x16_bf16(ap, bv1, c1, 0, 0, 0);

            float cv0[8], cv1[8];
            #pragma unroll
            for (int reg = 0; reg < 8; ++reg) {
                int row = (reg & 3) + 8 * (reg >> 2) + 4 * hi;
                const bf16* cp = ctx_tt + (size_t)(bh * 128 + rt * 16 + row) * 64;
                cv0[reg] = tof(cp[hl]);
                cv1[reg] = tof(cp[32 + hl]);
            }
            #pragma unroll
            for (int reg = 0; reg < 16; ++reg) {
                int row = (reg & 3) + 8 * (reg >> 2) + 4 * hi;
                int trow = row & 15;
                int lsel = (row < 16) ? l0 : l1;
                float w = wtab[wv][row], inv = itab[wv][row];
                float c0v = (reg < 8) ? cv0[reg] : cv0[reg - 8];
                float c1v = (reg < 8) ? cv1[reg] : cv1[reg - 8];
                size_t ob = (((size_t)b * TT + rt * 16 + trow) * LL + lsel) * HIDDEN + h * HD;
                out[ob + hl]      = (w * c0v + c0[reg]) * inv;
                out[ob + 32 + hl] = (w * c1v + c1[reg]) * inv;
            }
        }
    } else {
        const bf16* Pb = reinterpret_cast<const bf16*>(PWL);
        int qrow = 1024 + ((ml < 8) ? (l0 * LS + ml) : (l1 * LS + ml - 8));
        const bf16* qp = Qw + (size_t)qrow * HIDDEN + h * HD + quad * 8;
        bf16x8 a0 = *reinterpret_cast<const bf16x8*>(qp);
        bf16x8 a1 = *reinterpret_cast<const bf16x8*>(qp + 32);

        f32x4 sc[9];
        #pragma unroll
        for (int ct = 0; ct < 9; ++ct) {
            bf16x8 b0, b1;
            if (ct < 8) {
                const bf16* kp = Kw + (size_t)(b * SS + ct * 16 + ml) * HIDDEN + h * HD + quad * 8;
                b0 = *reinterpret_cast<const bf16x8*>(kp);
                b1 = *reinterpret_cast<const bf16x8*>(kp + 32);
            } else { b0 = kb0; b1 = kb1; }
            f32x4 zz = {0.f, 0.f, 0.f, 0.f};
            zz = __builtin_amdgcn_mfma_f32_16x16x32_bf16(a0, b0, zz, 0, 0, 0);
            zz = __builtin_amdgcn_mfma_f32_16x16x32_bf16(a1, b1, zz, 0, 0, 0);
            sc[ct] = zz;
        }

        float mx[4] = {-1e30f, -1e30f, -1e30f, -1e30f};
        #pragma unroll
        for (int ct = 0; ct < 9; ++ct) {
            #pragma unroll
            for (int reg = 0; reg < 4; ++reg) {
                int rq = quad * 4 + reg;
                float bc = (ct < 8) ? bias_t[ct * 16 + ml]
                                    : (((rq < 8) != (ml < 8)) ? -1e30f : bias_l[ml]);
                float v = sc[ct][reg] * 0.125f + bc;
                sc[ct][reg] = v;
                mx[reg] = fmaxf(mx[reg], v);
            }
        }
        #pragma unroll
        for (int reg = 0; reg < 4; ++reg)
            #pragma unroll
            for (int off = 1; off < 16; off <<= 1)
                mx[reg] = fmaxf(mx[reg], __shfl_xor(mx[reg], off));

        float Zs[4] = {0.f, 0.f, 0.f, 0.f};
        #pragma unroll
        for (int ct = 0; ct < 9; ++ct) {
            #pragma unroll
            for (int reg = 0; reg < 4; ++reg) {
                float e = __expf(sc[ct][reg] - mx[reg]);
                sc[ct][reg] = e;
                Zs[reg] += e;
            }
        }
        #pragma unroll
        for (int reg = 0; reg < 4; ++reg)
            #pragma unroll
            for (int off = 1; off < 16; off <<= 1)
                Zs[reg] += __shfl_xor(Zs[reg], off);
        float zi[4];
        #pragma unroll
        for (int reg = 0; reg < 4; ++reg) zi[reg] = 1.0f / Zs[reg];

        #pragma unroll
        for (int ct = 0; ct < 9; ++ct) {
            #pragma unroll
            for (int reg = 0; reg < 4; ++reg) {
                float e = sc[ct][reg];
                float ep = __shfl_xor(e, 1);
                if ((ml & 1) == 0)
                    PWL[(quad * 4 + reg) * 84 + ct * 8 + (ml >> 1)] =
                        (uint32_t)b16bits(e) | ((uint32_t)b16bits(ep) << 16);
            }
        }

        #pragma unroll
        for (int ct4 = 0; ct4 < 4; ++ct4) {
            f32x4 acc = {0.f, 0.f, 0.f, 0.f};
            #pragma unroll
            for (int ks = 0; ks < 5; ++ks) {
                bf16x8 ap = *reinterpret_cast<const bf16x8*>(Pb + ml * 168 + ks * 32 + quad * 8);
                bf16x8 bp = *reinterpret_cast<const bf16x8*>(Vtb + (ct4 * 16 + ml) * 168 + ks * 32 + quad * 8);
                acc = __builtin_amdgcn_mfma_f32_16x16x32_bf16(ap, bp, acc, 0, 0, 0);
            }
            #pragma unroll
            for (int reg = 0; reg < 4; ++reg) {
                int rq = quad * 4 + reg;
                int l = (rq < 8) ? l0 : l1;
                int t = SS + (rq & 7);
                out[(((size_t)b * TT + t) * LL + l) * HIDDEN + h * HD + ct4 * 16 + ml] =
                    acc[reg] * zi[reg];
            }
        }
    }
}

extern "C" void kernel_launch(void* const* d_in, const int* in_sizes, int n_in,
                              void* d_out, int out_size, void* d_ws, size_t ws_size,
                              hipStream_t stream)
{
    const float* tok   = (const float*)d_in[0];
    const float* lab   = (const float*)d_in[1];
    const float* tmask = (const float*)d_in[2];
    const float* lmask = (const float*)d_in[3];
    const float* Wq    = (const float*)d_in[4];
    const float* bq    = (const float*)d_in[5];
    const float* Wk    = (const float*)d_in[6];
    const float* bk    = (const float*)d_in[7];
    const float* Wv    = (const float*)d_in[8];
    const float* bv    = (const float*)d_in[9];

    // ws: Q/K/V bf16 (5,308,416) + ctx_tt bf16 (1,572,864) + m/d f32 (98,304)
    //     + Vt_g u32 (1,572,864) + Xb bf16 (1,769,472) + Wb bf16 (3,538,944)
    //     = 13,860,864 B.
    bf16* Qw = (bf16*)d_ws;
    bf16* Kw = Qw + (size_t)NROWS * HIDDEN;
    bf16* Vw = Kw + (size_t)NROWS * HIDDEN;
    bf16* ctx = Vw + (size_t)NROWS * HIDDEN;
    float* m_tt = (float*)(ctx + (size_t)BH * 128 * 64);
    float* d_tt = m_tt + BH * 128;
    uint32_t* Vt_g = (uint32_t*)(d_tt + BH * 128);
    uint16_t* Xb = (uint16_t*)(Vt_g + (size_t)BH * 4096);
    uint16_t* Wb = Xb + (size_t)NROWS * HIDDEN;

    cast_kernel<<<dim3(2592), 256, 0, stream>>>(tok, lab, Wq, Wk, Wv, Xb, Wb);
    qkv_kernel<<<dim3(18 * 18), 256, 0, stream>>>(
        Xb, Wb, bq, bk, bv, Qw, Kw, Vw);
    attn_tt_kernel<<<dim3(BH * 2), 256, 0, stream>>>(
        Qw, Kw, Vw, tmask, ctx, m_tt, d_tt, Vt_g);
    attn_merge_kernel<<<dim3(BB * NH * 8), 256, 0, stream>>>(
        Qw, Kw, Vw, Vt_g, ctx, m_tt, d_tt, tmask, lmask, (float*)d_out);
}